// Round 16
// baseline (3260.814 us; speedup 1.0000x reference)
//
#include <hip/hip_runtime.h>
#include <cstddef>
#include <cstdint>

#define T_STEPS 80
#define BATCH   256
#define DIM     4936
#define EMB     200
#define DE      5136
#define HID     512
#define SIXH    3072
#define FIVEH   2560
#define NCLS    151
#define NPACK   15504
#define NKT     156          // ceil(4936/32) for px; Kpad = 4992
#define NKT_H   16           // 512/32 for ps
#define NCOMB   2816         // 2560 (Wst) + 256 (Wout padded)
#define BUF2SZ  32768        // ushorts per mfma3 stage (64 KiB, single buffer)

typedef unsigned short ushort_t;
typedef short short8 __attribute__((ext_vector_type(8)));
typedef float f32x4 __attribute__((ext_vector_type(4)));
typedef float f32x16 __attribute__((ext_vector_type(16)));

__device__ inline ushort_t f2bf_rn(float x) {
    union { float f; uint32_t u; } v; v.f = x;
    uint32_t u = v.u;
    return (ushort_t)((u + 0x7FFFu + ((u >> 16) & 1u)) >> 16);
}
__device__ inline float bf2f(ushort_t b) {
    union { float f; uint32_t u; } v; v.u = ((uint32_t)b) << 16;
    return v.f;
}
__device__ inline float sigmoidf(float x) { return 1.f / (1.f + expf(-x)); }

// ---------------------------------------------------------------------------
// convert_split: src [ntiles*128 rows, ld] fp32 -> hi/lo bf16 in tiled layout
// out[mtile][ktile][kb(4)][row(128)][8]   (zero-padded for k >= kvalid)
// ---------------------------------------------------------------------------
__global__ __launch_bounds__(256) void convert_split(
    const float* __restrict__ src, int ld, int kvalid,
    ushort_t* __restrict__ hi, ushort_t* __restrict__ lo, int nktiles)
{
    __shared__ float s[128][33];
    const int tid = threadIdx.x;
    const int kt  = blockIdx.x;
    const int mt  = blockIdx.y;

#pragma unroll
    for (int it = 0; it < 4; ++it) {
        int idx = it * 256 + tid;          // 1024 float4 slots
        int row = idx >> 3;
        int f4  = idx & 7;
        int k   = kt * 32 + f4 * 4;
        const float* p = src + (size_t)(mt * 128 + row) * ld + k;
        float4 v;
        if (k + 3 < kvalid) v = *(const float4*)p;
        else {
            v.x = (k + 0) < kvalid ? p[0] : 0.f;
            v.y = (k + 1) < kvalid ? p[1] : 0.f;
            v.z = (k + 2) < kvalid ? p[2] : 0.f;
            v.w = (k + 3) < kvalid ? p[3] : 0.f;
        }
        s[row][f4 * 4 + 0] = v.x; s[row][f4 * 4 + 1] = v.y;
        s[row][f4 * 4 + 2] = v.z; s[row][f4 * 4 + 3] = v.w;
    }
    __syncthreads();

    const size_t base = ((size_t)mt * nktiles + kt) * 4096;
#pragma unroll
    for (int it = 0; it < 2; ++it) {
        int o   = it * 256 + tid;          // 512 chunks of 8 ushorts
        int kb  = o >> 7;
        int row = o & 127;
        alignas(16) ushort_t hbuf[8];
        alignas(16) ushort_t lbuf[8];
#pragma unroll
        for (int e = 0; e < 8; ++e) {
            float x = s[row][kb * 8 + e];
            ushort_t hh = f2bf_rn(x);
            float lof = x - bf2f(hh);
            hbuf[e] = hh;
            lbuf[e] = f2bf_rn(lof);
        }
        *(uint4*)(hi + base + (size_t)o * 8) = *(const uint4*)hbuf;
        *(uint4*)(lo + base + (size_t)o * 8) = *(const uint4*)lbuf;
    }
}

// ---------------------------------------------------------------------------
__device__ inline void gload16(const ushort_t* g, ushort_t* l) {
    __builtin_amdgcn_global_load_lds(
        (const __attribute__((address_space(1))) void*)g,
        (__attribute__((address_space(3))) void*)l, 16, 0, 0);
}

// ---------------------------------------------------------------------------
// mfma3: OUT[m,n] = bias[n] + sum_k A[m,k]*B[n,k] via 3-term split bf16.
// 256x256 tile, BK=32, 8 waves (2x4), wave tile 128x64, 32x32x16 MFMA.
// SINGLE-buffered 64 KiB LDS, 2 blocks/CU: per iter STAGE -> vmcnt(0) ->
// barrier -> compute -> barrier. Block A's stage/drain overlaps block B's
// MFMA on the same CU (m114 cross-block wave overlap) -- round-15's 1
// block/CU left those stalls naked (MfmaUtil 58%, Occupancy 22%).
// Panel-grouped XCD swizzle retained (FETCH 1.87 -> 1.23 GB in round 14).
// ---------------------------------------------------------------------------
__global__ __launch_bounds__(512, 2) void mfma3(
    const ushort_t* __restrict__ Ah, const ushort_t* __restrict__ Al,
    const ushort_t* __restrict__ Bh, const ushort_t* __restrict__ Bl,
    const float* __restrict__ bias, float* __restrict__ OUT,
    int nkt, int ldout, int nt)
{
    __shared__ __align__(16) ushort_t smem[BUF2SZ];   // 64 KiB

    const int tid  = threadIdx.x;
    const int wave = tid >> 6;
    const int lane = tid & 63;

    int mtb, ntb;
    {
        const int L = blockIdx.x;
        if ((nt & 7) == 0) {           // bijective panel-grouped XCD swizzle
            const int x = L & 7;       // XCD (hw: id % 8)
            const int s = L >> 3;      // slot within XCD
            mtb = x + 8 * (s / 12);
            ntb = s % 12;
        } else {                       // natural fallback
            mtb = L / 12;
            ntb = L % 12;
        }
    }
    const int wr = wave >> 2;        // 0..1: 128-row slab
    const int wc = wave & 3;         // 0..3: 64-col slab

    f32x16 acc[4][2];
#pragma unroll
    for (int i = 0; i < 4; ++i)
#pragma unroll
        for (int j = 0; j < 2; ++j)
#pragma unroll
            for (int r = 0; r < 16; ++r) acc[i][j][r] = 0.f;

    const size_t a0 = (size_t)(2 * mtb) * nkt * 4096;
    const size_t a1 = a0 + (size_t)nkt * 4096;
    const size_t b0 = (size_t)(2 * ntb) * nkt * 4096;
    const size_t b1 = b0 + (size_t)nkt * 4096;

    // LDS (ushort idx): Ah0 @0, Ah1 @4096, Al0 @8192, Al1 @12288,
    //                   Bh0 @16384, Bh1 @20480, Bl0 @24576, Bl1 @28672
#define STAGE1(kt_) do {                                            \
        const size_t ko = (size_t)(kt_) * 4096 + tid * 8;           \
        gload16(Ah + a0 + ko, smem + tid * 8);                      \
        gload16(Ah + a1 + ko, smem + 4096 + tid * 8);               \
        gload16(Al + a0 + ko, smem + 8192 + tid * 8);               \
        gload16(Al + a1 + ko, smem + 12288 + tid * 8);              \
        gload16(Bh + b0 + ko, smem + 16384 + tid * 8);              \
        gload16(Bh + b1 + ko, smem + 20480 + tid * 8);              \
        gload16(Bl + b0 + ko, smem + 24576 + tid * 8);              \
        gload16(Bl + b1 + ko, smem + 28672 + tid * 8);              \
    } while (0)

    const int lrow = lane & 31;          // row/col within 32-subtile
    const int kg   = lane >> 5;          // k-group (8 k values)
    const int aBase = wr * 4096;
    const int bBase = 16384 + (wc >> 1) * 4096;
    const int bCol  = (wc & 1) * 64;

    for (int kt = 0; kt < nkt; ++kt) {
        STAGE1(kt);
        asm volatile("s_waitcnt vmcnt(0)" ::: "memory");
        __builtin_amdgcn_sched_barrier(0);
        __builtin_amdgcn_s_barrier();          // stage visible to all waves

#pragma unroll
        for (int kh = 0; kh < 2; ++kh) {
            const int ko = (kh * 2 + kg) * 1024;
            short8 a_h[4], a_l[4], b_h[2], b_l[2];
#pragma unroll
            for (int ms = 0; ms < 4; ++ms) {
                const int ao = aBase + ko + (ms * 32 + lrow) * 8;
                a_h[ms] = *(const short8*)&smem[ao];
                a_l[ms] = *(const short8*)&smem[8192 + ao];
            }
#pragma unroll
            for (int ns = 0; ns < 2; ++ns) {
                const int bo = bBase + ko + (bCol + ns * 32 + lrow) * 8;
                b_h[ns] = *(const short8*)&smem[bo];
                b_l[ns] = *(const short8*)&smem[8192 + bo];
            }
#pragma unroll
            for (int ms = 0; ms < 4; ++ms)
#pragma unroll
                for (int ns = 0; ns < 2; ++ns) {
                    acc[ms][ns] = __builtin_amdgcn_mfma_f32_32x32x16_bf16(a_h[ms], b_h[ns], acc[ms][ns], 0, 0, 0);
                    acc[ms][ns] = __builtin_amdgcn_mfma_f32_32x32x16_bf16(a_h[ms], b_l[ns], acc[ms][ns], 0, 0, 0);
                    acc[ms][ns] = __builtin_amdgcn_mfma_f32_32x32x16_bf16(a_l[ms], b_h[ns], acc[ms][ns], 0, 0, 0);
                }
        }
        __builtin_amdgcn_s_barrier();          // all reads done before overwrite
    }
#undef STAGE1

#pragma unroll
    for (int ms = 0; ms < 4; ++ms)
#pragma unroll
        for (int ns = 0; ns < 2; ++ns) {
            const int col = ntb * 256 + wc * 64 + ns * 32 + (lane & 31);
            const float bv = bias[col];
            const int rowb = mtb * 256 + wr * 128 + ms * 32 + 4 * (lane >> 5);
#pragma unroll
            for (int r = 0; r < 16; ++r) {
                const int row = rowb + (r & 3) + 8 * (r >> 2);
                OUT[(size_t)row * ldout + col] = acc[ms][ns][r] + bv;
            }
        }
}

// ---------------------------------------------------------------------------
// ps_full: psF[m,n] = bias_comb[n] + sum_{k<512} h[m,k]*Wcomb[n,k]
// Wcomb = [Wst (2560 rows); Wout padded (256 rows)] -> N = 2816, 44 ntiles.
// 64x64 tile, FULL K (16 kt in 4 staged rounds through 64 KB LDS).
// 176 blocks. Deterministic (fixed kt order).
// ---------------------------------------------------------------------------
__global__ __launch_bounds__(256) void ps_full(
    const ushort_t* __restrict__ hH, const ushort_t* __restrict__ hL,
    const ushort_t* __restrict__ WcH, const ushort_t* __restrict__ WcL,
    const float* __restrict__ bias_comb,
    float* __restrict__ psF)   // [256][2816]
{
    __shared__ ushort_t sAh[8192], sAl[8192], sBh[8192], sBl[8192]; // 64 KiB

    const int tid  = threadIdx.x;
    const int wave = tid >> 6;
    const int lane = tid & 63;
    const int ntile = blockIdx.x;   // 0..43
    const int mtile = blockIdx.y;   // 0..3
    const int amt = mtile >> 1, arh = mtile & 1;
    const int bmt = ntile >> 1, brh = ntile & 1;
    const int wr = wave >> 1, wc = wave & 1;

    f32x4 acc[2][2];
#pragma unroll
    for (int i = 0; i < 2; ++i)
#pragma unroll
        for (int j = 0; j < 2; ++j) acc[i][j] = (f32x4){0.f, 0.f, 0.f, 0.f};

    const int lw    = wave * 512;
    const int lsrcA = wave * 1024 + arh * 512 + lane * 8;
    const int lsrcB = wave * 1024 + brh * 512 + lane * 8;
    const int kb = lane >> 4;
    const int lr = lane & 15;

    for (int r4nd = 0; r4nd < 4; ++r4nd) {
        if (r4nd) __syncthreads();          // prev round's reads done
#pragma unroll
        for (int ki = 0; ki < 4; ++ki) {
            const int kt = r4nd * 4 + ki;
            const size_t atile = ((size_t)(amt * NKT_H + kt)) * 4096;
            const size_t btile = ((size_t)(bmt * NKT_H + kt)) * 4096;
            gload16(hH  + atile + lsrcA, &sAh[ki * 2048 + lw]);
            gload16(hL  + atile + lsrcA, &sAl[ki * 2048 + lw]);
            gload16(WcH + btile + lsrcB, &sBh[ki * 2048 + lw]);
            gload16(WcL + btile + lsrcB, &sBl[ki * 2048 + lw]);
        }
        __syncthreads();   // drain: staged data visible

#pragma unroll
        for (int ki = 0; ki < 4; ++ki) {
            short8 ah[2], al[2], bh[2], bl[2];
#pragma unroll
            for (int i = 0; i < 2; ++i) {
                const int ao = ki * 2048 + kb * 512 + (wr * 32 + i * 16 + lr) * 8;
                ah[i] = *(const short8*)&sAh[ao];
                al[i] = *(const short8*)&sAl[ao];
            }
#pragma unroll
            for (int j = 0; j < 2; ++j) {
                const int bo = ki * 2048 + kb * 512 + (wc * 32 + j * 16 + lr) * 8;
                bh[j] = *(const short8*)&sBh[bo];
                bl[j] = *(const short8*)&sBl[bo];
            }
#pragma unroll
            for (int i = 0; i < 2; ++i)
#pragma unroll
                for (int j = 0; j < 2; ++j) {
                    acc[i][j] = __builtin_amdgcn_mfma_f32_16x16x32_bf16(ah[i], bh[j], acc[i][j], 0, 0, 0);
                    acc[i][j] = __builtin_amdgcn_mfma_f32_16x16x32_bf16(ah[i], bl[j], acc[i][j], 0, 0, 0);
                    acc[i][j] = __builtin_amdgcn_mfma_f32_16x16x32_bf16(al[i], bh[j], acc[i][j], 0, 0, 0);
                }
        }
    }

    float* out = psF + (size_t)(mtile * 64) * NCOMB + ntile * 64;
#pragma unroll
    for (int i = 0; i < 2; ++i) {
        const int row = wr * 32 + i * 16 + (lane >> 4) * 4;
#pragma unroll
        for (int j = 0; j < 2; ++j) {
            const int col = wc * 32 + j * 16 + (lane & 15);
            const float bv = bias_comb[ntile * 64 + col];
#pragma unroll
            for (int r = 0; r < 4; ++r)
                out[(size_t)(row + r) * NCOMB + col] = acc[i][j][r] + bv;
        }
    }
}

// ---------------------------------------------------------------------------
// ew_gemm: EW[m,n] = sum_k embed[m,k] * Win[n, 4936+k]   (m<152, K=200)
// ---------------------------------------------------------------------------
__global__ __launch_bounds__(256) void ew_gemm(
    const float* __restrict__ embed, const float* __restrict__ Win,
    float* __restrict__ EW)
{
    __shared__ float As[16][68];
    __shared__ float Bs[16][68];
    const int tid = threadIdx.x;
    const int tx  = tid & 15;
    const int ty  = tid >> 4;
    const int n0  = blockIdx.x * 64;
    const int m0  = blockIdx.y * 64;
    const int lrow = tid >> 2;
    const int lk   = (tid & 3) * 4;

    float acc[4][4];
#pragma unroll
    for (int i = 0; i < 4; ++i)
#pragma unroll
        for (int j = 0; j < 4; ++j) acc[i][j] = 0.f;

    for (int k0 = 0; k0 < EMB; k0 += 16) {
        int k = k0 + lk;
        float4 av = {0.f,0.f,0.f,0.f}, bv = {0.f,0.f,0.f,0.f};
        if (k < EMB) {
            int am = m0 + lrow;
            if (am < 152) av = *(const float4*)(embed + (size_t)am * EMB + k);
            bv = *(const float4*)(Win + (size_t)(n0 + lrow) * DE + DIM + k);
        }
        __syncthreads();
        As[lk + 0][lrow] = av.x; As[lk + 1][lrow] = av.y;
        As[lk + 2][lrow] = av.z; As[lk + 3][lrow] = av.w;
        Bs[lk + 0][lrow] = bv.x; Bs[lk + 1][lrow] = bv.y;
        Bs[lk + 2][lrow] = bv.z; Bs[lk + 3][lrow] = bv.w;
        __syncthreads();
#pragma unroll
        for (int kk = 0; kk < 16; ++kk) {
            float4 a4 = *(const float4*)&As[kk][ty * 4];
            float4 b4 = *(const float4*)&Bs[kk][tx * 4];
            float avr[4] = {a4.x, a4.y, a4.z, a4.w};
            float bvr[4] = {b4.x, b4.y, b4.z, b4.w};
#pragma unroll
            for (int i = 0; i < 4; ++i)
#pragma unroll
                for (int j = 0; j < 4; ++j)
                    acc[i][j] = fmaf(avr[i], bvr[j], acc[i][j]);
        }
    }
#pragma unroll
    for (int i = 0; i < 4; ++i) {
        int m = m0 + ty * 4 + i;
        if (m < 152) {
#pragma unroll
            for (int j = 0; j < 4; ++j)
                EW[(size_t)m * SIXH + n0 + tx * 4 + j] = acc[i][j];
        }
    }
}

// ---------------------------------------------------------------------------
// prep_misc: padW[256][512] = Wout rows 0..150 (zero-padded);
//            bias_comb[2816] = b_state (0..2559) | b_out (2560..2710) | 0
// ---------------------------------------------------------------------------
__global__ __launch_bounds__(256) void prep_misc(
    const float* __restrict__ Wout, const float* __restrict__ b_state,
    const float* __restrict__ b_out,
    float* __restrict__ padW, float* __restrict__ bc)
{
    int i = blockIdx.x * 256 + threadIdx.x;
    if (i < 256 * 512) {
        int row = i >> 9;
        padW[i] = (row < NCLS) ? Wout[i] : 0.f;
    }
    if (i < NCOMB) {
        float v;
        if (i < FIVEH)                 v = b_state[i];
        else if (i - FIVEH < NCLS)     v = b_out[i - FIVEH];
        else                           v = 0.f;
        bc[i] = v;
    }
}

// init: c = 0, tiled h hi/lo = 0 (first psF == bias). In-graph -> det.
__global__ __launch_bounds__(256) void init_state(
    float* __restrict__ c, ushort_t* __restrict__ hHt, ushort_t* __restrict__ hLt)
{
    int i = blockIdx.x * 256 + threadIdx.x;
    if (i < BATCH * HID) { c[i] = 0.f; hHt[i] = 0; hLt[i] = 0; }
}

// ---------------------------------------------------------------------------
// step_fused(t): 256 blocks x 1 batch row.
//  1) preds[t-1] = psF[b][2560+cls] (pre-biased, pred-deferral);
//     wave-parallel argmax -> commit[t-1] -> erow.
//  2) gates from px_t + EW[erow] + psF cols 0..2559 (bias included);
//     c,h update; h emits (tiled bf16 for next ps, fp32 for finalize).
// ---------------------------------------------------------------------------
__global__ __launch_bounds__(256) void step_fused(
    const float* __restrict__ px_t,        // [256, 3072]
    const float* __restrict__ EW,          // [152, 3072]
    const float* __restrict__ psF,         // [256, 2816]
    int first,
    ushort_t* __restrict__ hHt, ushort_t* __restrict__ hLt,
    float* __restrict__ c, float* __restrict__ hF,
    float* __restrict__ dists_prev,        // dists[t-1] (unused if first)
    int*   __restrict__ commit_prev)       // commits[t-1] (write; unused if first)
{
    __shared__ float hs[HID];
    __shared__ float preds_s[NCLS + 1];
    __shared__ int   commit_sh;

    const int tid = threadIdx.x;
    const int b   = blockIdx.x;

    int erow = 0;
    if (!first) {
        if (tid < NCLS) {
            float pr = psF[(size_t)b * NCOMB + 2560 + tid];
            preds_s[tid] = pr;
            dists_prev[(size_t)b * NCLS + tid] = pr;
        }
        __syncthreads();
        if (tid < 64) {
            // wave-parallel argmax over classes 1..150, first-max tie rule
            float bv = -__builtin_inff();
            int   bi = NCLS;
            for (int n = 1 + tid; n < NCLS; n += 64) {
                float v = preds_s[n];
                if (v > bv) { bv = v; bi = n; }
            }
#pragma unroll
            for (int off = 32; off; off >>= 1) {
                float ov = __shfl_down(bv, off);
                int   oi = __shfl_down(bi, off);
                if (ov > bv || (ov == bv && oi < bi)) { bv = ov; bi = oi; }
            }
            if (tid == 0) {
                commit_prev[b] = bi;
                commit_sh = bi;
            }
        }
        __syncthreads();
        erow = commit_sh + 1;
    }

    const float* ew = EW + (size_t)erow * SIXH;
    const float* px = px_t + (size_t)b * SIXH;
    const float* pp = psF + (size_t)b * NCOMB;

#pragma unroll
    for (int it = 0; it < 2; ++it) {
        const int u = it * 256 + tid;
        float p[6];
#pragma unroll
        for (int k2 = 0; k2 < 5; ++k2) {
            const int o = k2 * HID + u;
            p[k2] = px[o] + ew[o] + pp[o];   // pp already biased
        }
        p[5] = px[5 * HID + u] + ew[5 * HID + u];

        float i_g = sigmoidf(p[0]);
        float f_g = sigmoidf(p[1]);
        float m_i = tanhf(p[2]);
        float o_g = sigmoidf(p[3]);
        float c_new = i_g * m_i + f_g * c[(size_t)b * HID + u];
        float outv  = o_g * tanhf(c_new);
        float hw    = sigmoidf(p[4]);
        float h_new = hw * outv + (1.f - hw) * p[5];
        c[(size_t)b * HID + u]  = c_new;
        hF[(size_t)b * HID + u] = h_new;
        hs[u] = h_new;
    }
    __syncthreads();

    // tiled bf16 h emit for next step's ps GEMM
    if (tid < 128) {
        const int half = tid >> 6;
        const int ch   = tid & 63;
        const int mt   = b >> 7;
        const int row  = b & 127;
        const size_t off = ((size_t)(mt * NKT_H + (ch >> 2))) * 4096
                         + (size_t)(ch & 3) * 1024 + (size_t)row * 8;
        alignas(16) ushort_t buf[8];
        if (half == 0) {
#pragma unroll
            for (int e = 0; e < 8; ++e) buf[e] = f2bf_rn(hs[ch * 8 + e]);
            *(uint4*)(hHt + off) = *(const uint4*)buf;
        } else {
#pragma unroll
            for (int e = 0; e < 8; ++e) {
                float x = hs[ch * 8 + e];
                buf[e] = f2bf_rn(x - bf2f(f2bf_rn(x)));
            }
            *(uint4*)(hLt + off) = *(const uint4*)buf;
        }
    }
}

// ---------------------------------------------------------------------------
// finalize_last: preds for t = T-1 from fp32 h, argmax, dists+commits write.
// ---------------------------------------------------------------------------
__global__ __launch_bounds__(192) void finalize_last(
    const float* __restrict__ hF, const float* __restrict__ Wout,
    const float* __restrict__ b_out,
    float* __restrict__ dists_last, int* __restrict__ commits_last)
{
    __shared__ float hsh[HID];
    __shared__ float preds[NCLS + 1];
    const int b = blockIdx.x;
    const int tid = threadIdx.x;

    if (tid < 128) {
        float4 v = *(const float4*)(hF + (size_t)b * HID + tid * 4);
        *(float4*)&hsh[tid * 4] = v;
    }
    __syncthreads();
    if (tid < NCLS) {
        const float* w = Wout + (size_t)tid * HID;
        float s0 = 0.f, s1 = 0.f, s2 = 0.f, s3 = 0.f;
        for (int k = 0; k < HID; k += 4) {
            float4 w4 = *(const float4*)(w + k);
            float4 h4 = *(const float4*)&hsh[k];
            s0 = fmaf(h4.x, w4.x, s0);
            s1 = fmaf(h4.y, w4.y, s1);
            s2 = fmaf(h4.z, w4.z, s2);
            s3 = fmaf(h4.w, w4.w, s3);
        }
        float s = b_out[tid] + ((s0 + s1) + (s2 + s3));
        preds[tid] = s;
        dists_last[(size_t)b * NCLS + tid] = s;
    }
    __syncthreads();
    if (tid == 0) {
        int bi = 1; float bv = preds[1];
        for (int n = 2; n < NCLS; ++n) {
            float v = preds[n];
            if (v > bv) { bv = v; bi = n; }
        }
        commits_last[b] = bi;
    }
}

// ---------------------------------------------------------------------------
__global__ __launch_bounds__(192) void gather_out(
    const float* __restrict__ dists, const int* __restrict__ commits,
    const int* __restrict__ gidx, float* __restrict__ out)
{
    const int i = blockIdx.x;
    const int g = gidx[i];
    if (threadIdx.x < NCLS)
        out[(size_t)i * NCLS + threadIdx.x] = dists[(size_t)g * NCLS + threadIdx.x];
    if (threadIdx.x == NCLS)
        out[(size_t)NPACK * NCLS + i] = (float)commits[g];
}

// ---------------------------------------------------------------------------
extern "C" void kernel_launch(void* const* d_in, const int* in_sizes, int n_in,
                              void* d_out, int out_size, void* d_ws, size_t ws_size,
                              hipStream_t stream)
{
    const float* X      = (const float*)d_in[0];  // [80,256,4936]
    const float* embed  = (const float*)d_in[1];  // [152,200]
    const float* Win    = (const float*)d_in[2];  // [3072,5136]
    const float* b_in   = (const float*)d_in[3];
    const float* Wst    = (const float*)d_in[4];  // [2560,512]
    const float* b_st   = (const float*)d_in[5];
    const float* Wout   = (const float*)d_in[6];  // [151,512]
    const float* b_out  = (const float*)d_in[7];
    const int*   gidx   = (const int*)d_in[8];

    const size_t WN  = (size_t)24 * NKT * 4096;     // ushorts per Win-split array
    const size_t WCN = (size_t)22 * NKT_H * 4096;   // ushorts per Wcomb-split array
    const size_t HN  = (size_t)2 * NKT_H * 4096;    // ushorts per h-split array

    ushort_t* Wh  = (ushort_t*)d_ws;
    ushort_t* Wl  = Wh + WN;
    ushort_t* WcH = Wl + WN;
    ushort_t* WcL = WcH + WCN;
    ushort_t* hHt = WcL + WCN;
    ushort_t* hLt = hHt + HN;
    float* EW      = (float*)(hLt + HN);
    float* psF     = EW + (size_t)152 * SIXH;             // 256*2816
    float* bc      = psF + (size_t)BATCH * NCOMB;         // 2816
    float* c       = bc + NCOMB;
    float* hF      = c + (size_t)BATCH * HID;
    float* padW    = hF + (size_t)BATCH * HID;            // 256*512
    float* dists   = padW + (size_t)256 * HID;
    int* commits   = (int*)(dists + (size_t)T_STEPS * BATCH * NCLS);
    char* cbase    = (char*)(commits + T_STEPS * BATCH);

    size_t off = (size_t)(cbase - (char*)d_ws);
    off = (off + 255) & ~(size_t)255;
    const size_t per_t = (size_t)2 * 2 * NKT * 4096 * 2 + (size_t)BATCH * SIXH * 4;
    size_t rem = (ws_size > off) ? (ws_size - off) : 0;
    int CT = (int)(rem / per_t);
    if (CT > T_STEPS) CT = T_STEPS;
    if (CT < 1) CT = 1;

    ushort_t* Xh = (ushort_t*)((char*)d_ws + off);
    ushort_t* Xl = Xh + (size_t)2 * CT * NKT * 4096;
    float* px    = (float*)(Xl + (size_t)2 * CT * NKT * 4096);

    // one-time prep
    convert_split<<<dim3(NKT, 24), 256, 0, stream>>>(Win, DE, DIM, Wh, Wl, NKT);
    convert_split<<<dim3(NKT_H, 20), 256, 0, stream>>>(Wst, HID, HID, WcH, WcL, NKT_H);
    prep_misc<<<512, 256, 0, stream>>>(Wout, b_st, b_out, padW, bc);
    convert_split<<<dim3(NKT_H, 2), 256, 0, stream>>>(
        padW, HID, HID, WcH + (size_t)20 * NKT_H * 4096, WcL + (size_t)20 * NKT_H * 4096, NKT_H);
    ew_gemm<<<dim3(SIXH / 64, 3), 256, 0, stream>>>(embed, Win, EW);
    init_state<<<512, 256, 0, stream>>>(c, hHt, hLt);

    for (int t0 = 0; t0 < T_STEPS; t0 += CT) {
        int nt = T_STEPS - t0;
        if (nt > CT) nt = CT;
        convert_split<<<dim3(NKT, 2 * nt), 256, 0, stream>>>(
            X + (size_t)t0 * BATCH * DIM, DIM, DIM, Xh, Xl, NKT);
        mfma3<<<dim3((SIXH / 256) * nt), 512, 0, stream>>>(
            Xh, Xl, Wh, Wl, b_in, px, NKT, SIXH, nt);
        for (int t = t0; t < t0 + nt; ++t) {
            const int tp = (t > 0) ? t - 1 : 0;
            ps_full<<<dim3(44, 4), 256, 0, stream>>>(
                hHt, hLt, WcH, WcL, bc, psF);
            step_fused<<<BATCH, 256, 0, stream>>>(
                px + (size_t)(t - t0) * BATCH * SIXH, EW, psF,
                (t == 0) ? 1 : 0, hHt, hLt, c, hF,
                dists + (size_t)tp * BATCH * NCLS, commits + (size_t)tp * BATCH);
        }
    }

    finalize_last<<<BATCH, 192, 0, stream>>>(
        hF, Wout, b_out,
        dists + (size_t)(T_STEPS - 1) * BATCH * NCLS,
        commits + (size_t)(T_STEPS - 1) * BATCH);

    gather_out<<<NPACK, 192, 0, stream>>>(dists, commits, gidx, (float*)d_out);
}

// Round 17
// 2998.327 us; speedup vs baseline: 1.0875x; 1.0875x over previous
//
#include <hip/hip_runtime.h>
#include <cstddef>
#include <cstdint>

#define T_STEPS 80
#define BATCH   256
#define DIM     4936
#define EMB     200
#define DE      5136
#define HID     512
#define SIXH    3072
#define FIVEH   2560
#define NCLS    151
#define NPACK   15504
#define NKT     156          // ceil(4936/32) for px; Kpad = 4992
#define NKT_H   16           // 512/32 for ps
#define NCOMB   2816         // 2560 (Wst) + 256 (Wout padded)
#define BUF2SZ  32768        // ushorts per mfma3 pipeline stage (64 KiB)

typedef unsigned short ushort_t;
typedef short short8 __attribute__((ext_vector_type(8)));
typedef float f32x4 __attribute__((ext_vector_type(4)));
typedef float f32x16 __attribute__((ext_vector_type(16)));

__device__ inline ushort_t f2bf_rn(float x) {
    union { float f; uint32_t u; } v; v.f = x;
    uint32_t u = v.u;
    return (ushort_t)((u + 0x7FFFu + ((u >> 16) & 1u)) >> 16);
}
__device__ inline float bf2f(ushort_t b) {
    union { float f; uint32_t u; } v; v.u = ((uint32_t)b) << 16;
    return v.f;
}
__device__ inline float sigmoidf(float x) { return 1.f / (1.f + expf(-x)); }

// ---------------------------------------------------------------------------
// convert_split: src [ntiles*128 rows, ld] fp32 -> hi/lo bf16 in tiled layout
// out[mtile][ktile][kb(4)][row(128)][8]   (zero-padded for k >= kvalid)
// ---------------------------------------------------------------------------
__global__ __launch_bounds__(256) void convert_split(
    const float* __restrict__ src, int ld, int kvalid,
    ushort_t* __restrict__ hi, ushort_t* __restrict__ lo, int nktiles)
{
    __shared__ float s[128][33];
    const int tid = threadIdx.x;
    const int kt  = blockIdx.x;
    const int mt  = blockIdx.y;

#pragma unroll
    for (int it = 0; it < 4; ++it) {
        int idx = it * 256 + tid;          // 1024 float4 slots
        int row = idx >> 3;
        int f4  = idx & 7;
        int k   = kt * 32 + f4 * 4;
        const float* p = src + (size_t)(mt * 128 + row) * ld + k;
        float4 v;
        if (k + 3 < kvalid) v = *(const float4*)p;
        else {
            v.x = (k + 0) < kvalid ? p[0] : 0.f;
            v.y = (k + 1) < kvalid ? p[1] : 0.f;
            v.z = (k + 2) < kvalid ? p[2] : 0.f;
            v.w = (k + 3) < kvalid ? p[3] : 0.f;
        }
        s[row][f4 * 4 + 0] = v.x; s[row][f4 * 4 + 1] = v.y;
        s[row][f4 * 4 + 2] = v.z; s[row][f4 * 4 + 3] = v.w;
    }
    __syncthreads();

    const size_t base = ((size_t)mt * nktiles + kt) * 4096;
#pragma unroll
    for (int it = 0; it < 2; ++it) {
        int o   = it * 256 + tid;          // 512 chunks of 8 ushorts
        int kb  = o >> 7;
        int row = o & 127;
        alignas(16) ushort_t hbuf[8];
        alignas(16) ushort_t lbuf[8];
#pragma unroll
        for (int e = 0; e < 8; ++e) {
            float x = s[row][kb * 8 + e];
            ushort_t hh = f2bf_rn(x);
            float lof = x - bf2f(hh);
            hbuf[e] = hh;
            lbuf[e] = f2bf_rn(lof);
        }
        *(uint4*)(hi + base + (size_t)o * 8) = *(const uint4*)hbuf;
        *(uint4*)(lo + base + (size_t)o * 8) = *(const uint4*)lbuf;
    }
}

// ---------------------------------------------------------------------------
__device__ inline void gload16(const ushort_t* g, ushort_t* l) {
    __builtin_amdgcn_global_load_lds(
        (const __attribute__((address_space(1))) void*)g,
        (__attribute__((address_space(3))) void*)l, 16, 0, 0);
}

// ---------------------------------------------------------------------------
// mfma3: OUT[m,n] = bias[n] + sum_k A[m,k]*B[n,k] via 3-term split bf16.
// 256x256 tile, BK=32, 8 waves (2x4), wave tile 128x64, 32x32x16 MFMA.
// Double-buffered LDS (2 x 64 KiB, 1 block/CU), 1 barrier/iter, stage(kt+1)
// issued right after the barrier (one compute of prefetch slack).
// Panel-grouped XCD swizzle (round-14: FETCH 1.87 -> 1.23 GB).
// [Round-16 single-buffer 2-blk/CU REVERTED: exposed stage -> 43% MfmaUtil.
//  Round-15 kh stagger REVERTED: -1%. This config = best of 6 structures.]
// ---------------------------------------------------------------------------
__global__ __launch_bounds__(512, 1) void mfma3(
    const ushort_t* __restrict__ Ah, const ushort_t* __restrict__ Al,
    const ushort_t* __restrict__ Bh, const ushort_t* __restrict__ Bl,
    const float* __restrict__ bias, float* __restrict__ OUT,
    int nkt, int ldout, int nt)
{
    extern __shared__ __align__(16) ushort_t smem[];   // 2 * BUF2SZ ushorts

    const int tid  = threadIdx.x;
    const int wave = tid >> 6;
    const int lane = tid & 63;

    int mtb, ntb;
    {
        const int L = blockIdx.x;
        if ((nt & 7) == 0) {           // bijective panel-grouped XCD swizzle
            const int x = L & 7;       // XCD (hw: id % 8)
            const int s = L >> 3;      // slot within XCD
            mtb = x + 8 * (s / 12);
            ntb = s % 12;
        } else {                       // natural fallback
            mtb = L / 12;
            ntb = L % 12;
        }
    }
    const int wr = wave >> 2;        // 0..1: 128-row slab
    const int wc = wave & 3;         // 0..3: 64-col slab

    f32x16 acc[4][2];
#pragma unroll
    for (int i = 0; i < 4; ++i)
#pragma unroll
        for (int j = 0; j < 2; ++j)
#pragma unroll
            for (int r = 0; r < 16; ++r) acc[i][j][r] = 0.f;

    const size_t a0 = (size_t)(2 * mtb) * nkt * 4096;
    const size_t a1 = a0 + (size_t)nkt * 4096;
    const size_t b0 = (size_t)(2 * ntb) * nkt * 4096;
    const size_t b1 = b0 + (size_t)nkt * 4096;

    // LDS per stage (ushort idx): Ah0 @0, Ah1 @4096, Al0 @8192, Al1 @12288,
    //                             Bh0 @16384, Bh1 @20480, Bl0 @24576, Bl1 @28672
#define STAGE2(slot, kt_) do {                                      \
        ushort_t* d = smem + (slot) * BUF2SZ;                       \
        const size_t ko = (size_t)(kt_) * 4096 + tid * 8;           \
        gload16(Ah + a0 + ko, d + tid * 8);                         \
        gload16(Ah + a1 + ko, d + 4096 + tid * 8);                  \
        gload16(Al + a0 + ko, d + 8192 + tid * 8);                  \
        gload16(Al + a1 + ko, d + 12288 + tid * 8);                 \
        gload16(Bh + b0 + ko, d + 16384 + tid * 8);                 \
        gload16(Bh + b1 + ko, d + 20480 + tid * 8);                 \
        gload16(Bl + b0 + ko, d + 24576 + tid * 8);                 \
        gload16(Bl + b1 + ko, d + 28672 + tid * 8);                 \
    } while (0)

    const int lrow = lane & 31;          // row/col within 32-subtile
    const int kg   = lane >> 5;          // k-group (8 k values)
    const int aBase = wr * 4096;
    const int bBase = 16384 + (wc >> 1) * 4096;
    const int bCol  = (wc & 1) * 64;

    STAGE2(0, 0);

    for (int kt = 0; kt < nkt; ++kt) {
        asm volatile("s_waitcnt vmcnt(0)" ::: "memory");
        __builtin_amdgcn_sched_barrier(0);
        __builtin_amdgcn_s_barrier();          // stage(kt) visible; prev reads done
        if (kt + 1 < nkt) STAGE2((kt + 1) & 1, kt + 1);

        const ushort_t* p = smem + (kt & 1) * BUF2SZ;
#pragma unroll
        for (int kh = 0; kh < 2; ++kh) {
            const int ko = (kh * 2 + kg) * 1024;
            short8 a_h[4], a_l[4], b_h[2], b_l[2];
#pragma unroll
            for (int ms = 0; ms < 4; ++ms) {
                const int ao = aBase + ko + (ms * 32 + lrow) * 8;
                a_h[ms] = *(const short8*)&p[ao];
                a_l[ms] = *(const short8*)&p[8192 + ao];
            }
#pragma unroll
            for (int ns = 0; ns < 2; ++ns) {
                const int bo = bBase + ko + (bCol + ns * 32 + lrow) * 8;
                b_h[ns] = *(const short8*)&p[bo];
                b_l[ns] = *(const short8*)&p[8192 + bo];
            }
#pragma unroll
            for (int ms = 0; ms < 4; ++ms)
#pragma unroll
                for (int ns = 0; ns < 2; ++ns) {
                    acc[ms][ns] = __builtin_amdgcn_mfma_f32_32x32x16_bf16(a_h[ms], b_h[ns], acc[ms][ns], 0, 0, 0);
                    acc[ms][ns] = __builtin_amdgcn_mfma_f32_32x32x16_bf16(a_h[ms], b_l[ns], acc[ms][ns], 0, 0, 0);
                    acc[ms][ns] = __builtin_amdgcn_mfma_f32_32x32x16_bf16(a_l[ms], b_h[ns], acc[ms][ns], 0, 0, 0);
                }
        }
    }
#undef STAGE2

#pragma unroll
    for (int ms = 0; ms < 4; ++ms)
#pragma unroll
        for (int ns = 0; ns < 2; ++ns) {
            const int col = ntb * 256 + wc * 64 + ns * 32 + (lane & 31);
            const float bv = bias[col];
            const int rowb = mtb * 256 + wr * 128 + ms * 32 + 4 * (lane >> 5);
#pragma unroll
            for (int r = 0; r < 16; ++r) {
                const int row = rowb + (r & 3) + 8 * (r >> 2);
                OUT[(size_t)row * ldout + col] = acc[ms][ns][r] + bv;
            }
        }
}

// ---------------------------------------------------------------------------
// ps_full: psF[m,n] = bias_comb[n] + sum_{k<512} h[m,k]*Wcomb[n,k]
// Wcomb = [Wst (2560 rows); Wout padded (256 rows)] -> N = 2816, 44 ntiles.
// 64x64 tile, FULL K (16 kt in 4 staged rounds through 64 KB LDS).
// 176 blocks. Deterministic (fixed kt order).
// ---------------------------------------------------------------------------
__global__ __launch_bounds__(256) void ps_full(
    const ushort_t* __restrict__ hH, const ushort_t* __restrict__ hL,
    const ushort_t* __restrict__ WcH, const ushort_t* __restrict__ WcL,
    const float* __restrict__ bias_comb,
    float* __restrict__ psF)   // [256][2816]
{
    __shared__ ushort_t sAh[8192], sAl[8192], sBh[8192], sBl[8192]; // 64 KiB

    const int tid  = threadIdx.x;
    const int wave = tid >> 6;
    const int lane = tid & 63;
    const int ntile = blockIdx.x;   // 0..43
    const int mtile = blockIdx.y;   // 0..3
    const int amt = mtile >> 1, arh = mtile & 1;
    const int bmt = ntile >> 1, brh = ntile & 1;
    const int wr = wave >> 1, wc = wave & 1;

    f32x4 acc[2][2];
#pragma unroll
    for (int i = 0; i < 2; ++i)
#pragma unroll
        for (int j = 0; j < 2; ++j) acc[i][j] = (f32x4){0.f, 0.f, 0.f, 0.f};

    const int lw    = wave * 512;
    const int lsrcA = wave * 1024 + arh * 512 + lane * 8;
    const int lsrcB = wave * 1024 + brh * 512 + lane * 8;
    const int kb = lane >> 4;
    const int lr = lane & 15;

    for (int r4nd = 0; r4nd < 4; ++r4nd) {
        if (r4nd) __syncthreads();          // prev round's reads done
#pragma unroll
        for (int ki = 0; ki < 4; ++ki) {
            const int kt = r4nd * 4 + ki;
            const size_t atile = ((size_t)(amt * NKT_H + kt)) * 4096;
            const size_t btile = ((size_t)(bmt * NKT_H + kt)) * 4096;
            gload16(hH  + atile + lsrcA, &sAh[ki * 2048 + lw]);
            gload16(hL  + atile + lsrcA, &sAl[ki * 2048 + lw]);
            gload16(WcH + btile + lsrcB, &sBh[ki * 2048 + lw]);
            gload16(WcL + btile + lsrcB, &sBl[ki * 2048 + lw]);
        }
        __syncthreads();   // drain: staged data visible

#pragma unroll
        for (int ki = 0; ki < 4; ++ki) {
            short8 ah[2], al[2], bh[2], bl[2];
#pragma unroll
            for (int i = 0; i < 2; ++i) {
                const int ao = ki * 2048 + kb * 512 + (wr * 32 + i * 16 + lr) * 8;
                ah[i] = *(const short8*)&sAh[ao];
                al[i] = *(const short8*)&sAl[ao];
            }
#pragma unroll
            for (int j = 0; j < 2; ++j) {
                const int bo = ki * 2048 + kb * 512 + (wc * 32 + j * 16 + lr) * 8;
                bh[j] = *(const short8*)&sBh[bo];
                bl[j] = *(const short8*)&sBl[bo];
            }
#pragma unroll
            for (int i = 0; i < 2; ++i)
#pragma unroll
                for (int j = 0; j < 2; ++j) {
                    acc[i][j] = __builtin_amdgcn_mfma_f32_16x16x32_bf16(ah[i], bh[j], acc[i][j], 0, 0, 0);
                    acc[i][j] = __builtin_amdgcn_mfma_f32_16x16x32_bf16(ah[i], bl[j], acc[i][j], 0, 0, 0);
                    acc[i][j] = __builtin_amdgcn_mfma_f32_16x16x32_bf16(al[i], bh[j], acc[i][j], 0, 0, 0);
                }
        }
    }

    float* out = psF + (size_t)(mtile * 64) * NCOMB + ntile * 64;
#pragma unroll
    for (int i = 0; i < 2; ++i) {
        const int row = wr * 32 + i * 16 + (lane >> 4) * 4;
#pragma unroll
        for (int j = 0; j < 2; ++j) {
            const int col = wc * 32 + j * 16 + (lane & 15);
            const float bv = bias_comb[ntile * 64 + col];
#pragma unroll
            for (int r = 0; r < 4; ++r)
                out[(size_t)(row + r) * NCOMB + col] = acc[i][j][r] + bv;
        }
    }
}

// ---------------------------------------------------------------------------
// ew_gemm: EW[m,n] = sum_k embed[m,k] * Win[n, 4936+k]   (m<152, K=200)
// ---------------------------------------------------------------------------
__global__ __launch_bounds__(256) void ew_gemm(
    const float* __restrict__ embed, const float* __restrict__ Win,
    float* __restrict__ EW)
{
    __shared__ float As[16][68];
    __shared__ float Bs[16][68];
    const int tid = threadIdx.x;
    const int tx  = tid & 15;
    const int ty  = tid >> 4;
    const int n0  = blockIdx.x * 64;
    const int m0  = blockIdx.y * 64;
    const int lrow = tid >> 2;
    const int lk   = (tid & 3) * 4;

    float acc[4][4];
#pragma unroll
    for (int i = 0; i < 4; ++i)
#pragma unroll
        for (int j = 0; j < 4; ++j) acc[i][j] = 0.f;

    for (int k0 = 0; k0 < EMB; k0 += 16) {
        int k = k0 + lk;
        float4 av = {0.f,0.f,0.f,0.f}, bv = {0.f,0.f,0.f,0.f};
        if (k < EMB) {
            int am = m0 + lrow;
            if (am < 152) av = *(const float4*)(embed + (size_t)am * EMB + k);
            bv = *(const float4*)(Win + (size_t)(n0 + lrow) * DE + DIM + k);
        }
        __syncthreads();
        As[lk + 0][lrow] = av.x; As[lk + 1][lrow] = av.y;
        As[lk + 2][lrow] = av.z; As[lk + 3][lrow] = av.w;
        Bs[lk + 0][lrow] = bv.x; Bs[lk + 1][lrow] = bv.y;
        Bs[lk + 2][lrow] = bv.z; Bs[lk + 3][lrow] = bv.w;
        __syncthreads();
#pragma unroll
        for (int kk = 0; kk < 16; ++kk) {
            float4 a4 = *(const float4*)&As[kk][ty * 4];
            float4 b4 = *(const float4*)&Bs[kk][tx * 4];
            float avr[4] = {a4.x, a4.y, a4.z, a4.w};
            float bvr[4] = {b4.x, b4.y, b4.z, b4.w};
#pragma unroll
            for (int i = 0; i < 4; ++i)
#pragma unroll
                for (int j = 0; j < 4; ++j)
                    acc[i][j] = fmaf(avr[i], bvr[j], acc[i][j]);
        }
    }
#pragma unroll
    for (int i = 0; i < 4; ++i) {
        int m = m0 + ty * 4 + i;
        if (m < 152) {
#pragma unroll
            for (int j = 0; j < 4; ++j)
                EW[(size_t)m * SIXH + n0 + tx * 4 + j] = acc[i][j];
        }
    }
}

// ---------------------------------------------------------------------------
// prep_misc: padW[256][512] = Wout rows 0..150 (zero-padded);
//            bias_comb[2816] = b_state (0..2559) | b_out (2560..2710) | 0
// ---------------------------------------------------------------------------
__global__ __launch_bounds__(256) void prep_misc(
    const float* __restrict__ Wout, const float* __restrict__ b_state,
    const float* __restrict__ b_out,
    float* __restrict__ padW, float* __restrict__ bc)
{
    int i = blockIdx.x * 256 + threadIdx.x;
    if (i < 256 * 512) {
        int row = i >> 9;
        padW[i] = (row < NCLS) ? Wout[i] : 0.f;
    }
    if (i < NCOMB) {
        float v;
        if (i < FIVEH)                 v = b_state[i];
        else if (i - FIVEH < NCLS)     v = b_out[i - FIVEH];
        else                           v = 0.f;
        bc[i] = v;
    }
}

// init: c = 0, tiled h hi/lo = 0 (first psF == bias). In-graph -> det.
__global__ __launch_bounds__(256) void init_state(
    float* __restrict__ c, ushort_t* __restrict__ hHt, ushort_t* __restrict__ hLt)
{
    int i = blockIdx.x * 256 + threadIdx.x;
    if (i < BATCH * HID) { c[i] = 0.f; hHt[i] = 0; hLt[i] = 0; }
}

// ---------------------------------------------------------------------------
// step_fused(t): 256 blocks x 1 batch row.
//  1) preds[t-1] = psF[b][2560+cls] (pre-biased, pred-deferral);
//     wave-parallel argmax -> commit[t-1] -> erow.
//  2) gates from px_t + EW[erow] + psF cols 0..2559 (bias included);
//     c,h update; h emits (tiled bf16 for next ps, fp32 for finalize).
// ---------------------------------------------------------------------------
__global__ __launch_bounds__(256) void step_fused(
    const float* __restrict__ px_t,        // [256, 3072]
    const float* __restrict__ EW,          // [152, 3072]
    const float* __restrict__ psF,         // [256, 2816]
    int first,
    ushort_t* __restrict__ hHt, ushort_t* __restrict__ hLt,
    float* __restrict__ c, float* __restrict__ hF,
    float* __restrict__ dists_prev,        // dists[t-1] (unused if first)
    int*   __restrict__ commit_prev)       // commits[t-1] (write; unused if first)
{
    __shared__ float hs[HID];
    __shared__ float preds_s[NCLS + 1];
    __shared__ int   commit_sh;

    const int tid = threadIdx.x;
    const int b   = blockIdx.x;

    int erow = 0;
    if (!first) {
        if (tid < NCLS) {
            float pr = psF[(size_t)b * NCOMB + 2560 + tid];
            preds_s[tid] = pr;
            dists_prev[(size_t)b * NCLS + tid] = pr;
        }
        __syncthreads();
        if (tid < 64) {
            // wave-parallel argmax over classes 1..150, first-max tie rule
            float bv = -__builtin_inff();
            int   bi = NCLS;
            for (int n = 1 + tid; n < NCLS; n += 64) {
                float v = preds_s[n];
                if (v > bv) { bv = v; bi = n; }
            }
#pragma unroll
            for (int off = 32; off; off >>= 1) {
                float ov = __shfl_down(bv, off);
                int   oi = __shfl_down(bi, off);
                if (ov > bv || (ov == bv && oi < bi)) { bv = ov; bi = oi; }
            }
            if (tid == 0) {
                commit_prev[b] = bi;
                commit_sh = bi;
            }
        }
        __syncthreads();
        erow = commit_sh + 1;
    }

    const float* ew = EW + (size_t)erow * SIXH;
    const float* px = px_t + (size_t)b * SIXH;
    const float* pp = psF + (size_t)b * NCOMB;

#pragma unroll
    for (int it = 0; it < 2; ++it) {
        const int u = it * 256 + tid;
        float p[6];
#pragma unroll
        for (int k2 = 0; k2 < 5; ++k2) {
            const int o = k2 * HID + u;
            p[k2] = px[o] + ew[o] + pp[o];   // pp already biased
        }
        p[5] = px[5 * HID + u] + ew[5 * HID + u];

        float i_g = sigmoidf(p[0]);
        float f_g = sigmoidf(p[1]);
        float m_i = tanhf(p[2]);
        float o_g = sigmoidf(p[3]);
        float c_new = i_g * m_i + f_g * c[(size_t)b * HID + u];
        float outv  = o_g * tanhf(c_new);
        float hw    = sigmoidf(p[4]);
        float h_new = hw * outv + (1.f - hw) * p[5];
        c[(size_t)b * HID + u]  = c_new;
        hF[(size_t)b * HID + u] = h_new;
        hs[u] = h_new;
    }
    __syncthreads();

    // tiled bf16 h emit for next step's ps GEMM
    if (tid < 128) {
        const int half = tid >> 6;
        const int ch   = tid & 63;
        const int mt   = b >> 7;
        const int row  = b & 127;
        const size_t off = ((size_t)(mt * NKT_H + (ch >> 2))) * 4096
                         + (size_t)(ch & 3) * 1024 + (size_t)row * 8;
        alignas(16) ushort_t buf[8];
        if (half == 0) {
#pragma unroll
            for (int e = 0; e < 8; ++e) buf[e] = f2bf_rn(hs[ch * 8 + e]);
            *(uint4*)(hHt + off) = *(const uint4*)buf;
        } else {
#pragma unroll
            for (int e = 0; e < 8; ++e) {
                float x = hs[ch * 8 + e];
                buf[e] = f2bf_rn(x - bf2f(f2bf_rn(x)));
            }
            *(uint4*)(hLt + off) = *(const uint4*)buf;
        }
    }
}

// ---------------------------------------------------------------------------
// finalize_last: preds for t = T-1 from fp32 h, argmax, dists+commits write.
// ---------------------------------------------------------------------------
__global__ __launch_bounds__(192) void finalize_last(
    const float* __restrict__ hF, const float* __restrict__ Wout,
    const float* __restrict__ b_out,
    float* __restrict__ dists_last, int* __restrict__ commits_last)
{
    __shared__ float hsh[HID];
    __shared__ float preds[NCLS + 1];
    const int b = blockIdx.x;
    const int tid = threadIdx.x;

    if (tid < 128) {
        float4 v = *(const float4*)(hF + (size_t)b * HID + tid * 4);
        *(float4*)&hsh[tid * 4] = v;
    }
    __syncthreads();
    if (tid < NCLS) {
        const float* w = Wout + (size_t)tid * HID;
        float s0 = 0.f, s1 = 0.f, s2 = 0.f, s3 = 0.f;
        for (int k = 0; k < HID; k += 4) {
            float4 w4 = *(const float4*)(w + k);
            float4 h4 = *(const float4*)&hsh[k];
            s0 = fmaf(h4.x, w4.x, s0);
            s1 = fmaf(h4.y, w4.y, s1);
            s2 = fmaf(h4.z, w4.z, s2);
            s3 = fmaf(h4.w, w4.w, s3);
        }
        float s = b_out[tid] + ((s0 + s1) + (s2 + s3));
        preds[tid] = s;
        dists_last[(size_t)b * NCLS + tid] = s;
    }
    __syncthreads();
    if (tid == 0) {
        int bi = 1; float bv = preds[1];
        for (int n = 2; n < NCLS; ++n) {
            float v = preds[n];
            if (v > bv) { bv = v; bi = n; }
        }
        commits_last[b] = bi;
    }
}

// ---------------------------------------------------------------------------
__global__ __launch_bounds__(192) void gather_out(
    const float* __restrict__ dists, const int* __restrict__ commits,
    const int* __restrict__ gidx, float* __restrict__ out)
{
    const int i = blockIdx.x;
    const int g = gidx[i];
    if (threadIdx.x < NCLS)
        out[(size_t)i * NCLS + threadIdx.x] = dists[(size_t)g * NCLS + threadIdx.x];
    if (threadIdx.x == NCLS)
        out[(size_t)NPACK * NCLS + i] = (float)commits[g];
}

// ---------------------------------------------------------------------------
extern "C" void kernel_launch(void* const* d_in, const int* in_sizes, int n_in,
                              void* d_out, int out_size, void* d_ws, size_t ws_size,
                              hipStream_t stream)
{
    const float* X      = (const float*)d_in[0];  // [80,256,4936]
    const float* embed  = (const float*)d_in[1];  // [152,200]
    const float* Win    = (const float*)d_in[2];  // [3072,5136]
    const float* b_in   = (const float*)d_in[3];
    const float* Wst    = (const float*)d_in[4];  // [2560,512]
    const float* b_st   = (const float*)d_in[5];
    const float* Wout   = (const float*)d_in[6];  // [151,512]
    const float* b_out  = (const float*)d_in[7];
    const int*   gidx   = (const int*)d_in[8];

    // raise dynamic-LDS cap for mfma3 (idempotent; capture-safe host call)
    hipFuncSetAttribute((const void*)mfma3,
                        hipFuncAttributeMaxDynamicSharedMemorySize,
                        2 * BUF2SZ * 2);

    const size_t WN  = (size_t)24 * NKT * 4096;     // ushorts per Win-split array
    const size_t WCN = (size_t)22 * NKT_H * 4096;   // ushorts per Wcomb-split array
    const size_t HN  = (size_t)2 * NKT_H * 4096;    // ushorts per h-split array

    ushort_t* Wh  = (ushort_t*)d_ws;
    ushort_t* Wl  = Wh + WN;
    ushort_t* WcH = Wl + WN;
    ushort_t* WcL = WcH + WCN;
    ushort_t* hHt = WcL + WCN;
    ushort_t* hLt = hHt + HN;
    float* EW      = (float*)(hLt + HN);
    float* psF     = EW + (size_t)152 * SIXH;             // 256*2816
    float* bc      = psF + (size_t)BATCH * NCOMB;         // 2816
    float* c       = bc + NCOMB;
    float* hF      = c + (size_t)BATCH * HID;
    float* padW    = hF + (size_t)BATCH * HID;            // 256*512
    float* dists   = padW + (size_t)256 * HID;
    int* commits   = (int*)(dists + (size_t)T_STEPS * BATCH * NCLS);
    char* cbase    = (char*)(commits + T_STEPS * BATCH);

    size_t off = (size_t)(cbase - (char*)d_ws);
    off = (off + 255) & ~(size_t)255;
    const size_t per_t = (size_t)2 * 2 * NKT * 4096 * 2 + (size_t)BATCH * SIXH * 4;
    size_t rem = (ws_size > off) ? (ws_size - off) : 0;
    int CT = (int)(rem / per_t);
    if (CT > T_STEPS) CT = T_STEPS;
    if (CT < 1) CT = 1;

    ushort_t* Xh = (ushort_t*)((char*)d_ws + off);
    ushort_t* Xl = Xh + (size_t)2 * CT * NKT * 4096;
    float* px    = (float*)(Xl + (size_t)2 * CT * NKT * 4096);

    // one-time prep
    convert_split<<<dim3(NKT, 24), 256, 0, stream>>>(Win, DE, DIM, Wh, Wl, NKT);
    convert_split<<<dim3(NKT_H, 20), 256, 0, stream>>>(Wst, HID, HID, WcH, WcL, NKT_H);
    prep_misc<<<512, 256, 0, stream>>>(Wout, b_st, b_out, padW, bc);
    convert_split<<<dim3(NKT_H, 2), 256, 0, stream>>>(
        padW, HID, HID, WcH + (size_t)20 * NKT_H * 4096, WcL + (size_t)20 * NKT_H * 4096, NKT_H);
    ew_gemm<<<dim3(SIXH / 64, 3), 256, 0, stream>>>(embed, Win, EW);
    init_state<<<512, 256, 0, stream>>>(c, hHt, hLt);

    for (int t0 = 0; t0 < T_STEPS; t0 += CT) {
        int nt = T_STEPS - t0;
        if (nt > CT) nt = CT;
        convert_split<<<dim3(NKT, 2 * nt), 256, 0, stream>>>(
            X + (size_t)t0 * BATCH * DIM, DIM, DIM, Xh, Xl, NKT);
        mfma3<<<dim3((SIXH / 256) * nt), 512, 2 * BUF2SZ * 2, stream>>>(
            Xh, Xl, Wh, Wl, b_in, px, NKT, SIXH, nt);
        for (int t = t0; t < t0 + nt; ++t) {
            const int tp = (t > 0) ? t - 1 : 0;
            ps_full<<<dim3(44, 4), 256, 0, stream>>>(
                hHt, hLt, WcH, WcL, bc, psF);
            step_fused<<<BATCH, 256, 0, stream>>>(
                px + (size_t)(t - t0) * BATCH * SIXH, EW, psF,
                (t == 0) ? 1 : 0, hHt, hLt, c, hF,
                dists + (size_t)tp * BATCH * NCLS, commits + (size_t)tp * BATCH);
        }
    }

    finalize_last<<<BATCH, 192, 0, stream>>>(
        hF, Wout, b_out,
        dists + (size_t)(T_STEPS - 1) * BATCH * NCLS,
        commits + (size_t)(T_STEPS - 1) * BATCH);

    gather_out<<<NPACK, 192, 0, stream>>>(dists, commits, gidx, (float*)d_out);
}

// Round 18
// 2848.668 us; speedup vs baseline: 1.1447x; 1.0525x over previous
//
#include <hip/hip_runtime.h>
#include <cstddef>
#include <cstdint>

#define T_STEPS 80
#define BATCH   256
#define DIM     4936
#define EMB     200
#define DE      5136
#define HID     512
#define SIXH    3072
#define FIVEH   2560
#define NCLS    151
#define NPACK   15504
#define NKT     156          // ceil(4936/32) for px; Kpad = 4992
#define NKT_H   16           // 512/32 for ps
#define NCOMB   2816         // 2560 (Wst) + 256 (Wout padded)
#define BUF2SZ  32768        // ushorts per mfma3 pipeline stage (64 KiB)
#define PSBUF   32768        // ushorts per ps_full pipeline stage (64 KiB)

typedef unsigned short ushort_t;
typedef short short8 __attribute__((ext_vector_type(8)));
typedef float f32x4 __attribute__((ext_vector_type(4)));
typedef float f32x16 __attribute__((ext_vector_type(16)));

__device__ inline ushort_t f2bf_rn(float x) {
    union { float f; uint32_t u; } v; v.f = x;
    uint32_t u = v.u;
    return (ushort_t)((u + 0x7FFFu + ((u >> 16) & 1u)) >> 16);
}
__device__ inline float bf2f(ushort_t b) {
    union { float f; uint32_t u; } v; v.u = ((uint32_t)b) << 16;
    return v.f;
}
__device__ inline float sigmoidf(float x) { return 1.f / (1.f + expf(-x)); }

// ---------------------------------------------------------------------------
// convert_split: src [ntiles*128 rows, ld] fp32 -> hi/lo bf16 in tiled layout
// out[mtile][ktile][kb(4)][row(128)][8]   (zero-padded for k >= kvalid)
// ---------------------------------------------------------------------------
__global__ __launch_bounds__(256) void convert_split(
    const float* __restrict__ src, int ld, int kvalid,
    ushort_t* __restrict__ hi, ushort_t* __restrict__ lo, int nktiles)
{
    __shared__ float s[128][33];
    const int tid = threadIdx.x;
    const int kt  = blockIdx.x;
    const int mt  = blockIdx.y;

#pragma unroll
    for (int it = 0; it < 4; ++it) {
        int idx = it * 256 + tid;          // 1024 float4 slots
        int row = idx >> 3;
        int f4  = idx & 7;
        int k   = kt * 32 + f4 * 4;
        const float* p = src + (size_t)(mt * 128 + row) * ld + k;
        float4 v;
        if (k + 3 < kvalid) v = *(const float4*)p;
        else {
            v.x = (k + 0) < kvalid ? p[0] : 0.f;
            v.y = (k + 1) < kvalid ? p[1] : 0.f;
            v.z = (k + 2) < kvalid ? p[2] : 0.f;
            v.w = (k + 3) < kvalid ? p[3] : 0.f;
        }
        s[row][f4 * 4 + 0] = v.x; s[row][f4 * 4 + 1] = v.y;
        s[row][f4 * 4 + 2] = v.z; s[row][f4 * 4 + 3] = v.w;
    }
    __syncthreads();

    const size_t base = ((size_t)mt * nktiles + kt) * 4096;
#pragma unroll
    for (int it = 0; it < 2; ++it) {
        int o   = it * 256 + tid;          // 512 chunks of 8 ushorts
        int kb  = o >> 7;
        int row = o & 127;
        alignas(16) ushort_t hbuf[8];
        alignas(16) ushort_t lbuf[8];
#pragma unroll
        for (int e = 0; e < 8; ++e) {
            float x = s[row][kb * 8 + e];
            ushort_t hh = f2bf_rn(x);
            float lof = x - bf2f(hh);
            hbuf[e] = hh;
            lbuf[e] = f2bf_rn(lof);
        }
        *(uint4*)(hi + base + (size_t)o * 8) = *(const uint4*)hbuf;
        *(uint4*)(lo + base + (size_t)o * 8) = *(const uint4*)lbuf;
    }
}

// ---------------------------------------------------------------------------
__device__ inline void gload16(const ushort_t* g, ushort_t* l) {
    __builtin_amdgcn_global_load_lds(
        (const __attribute__((address_space(1))) void*)g,
        (__attribute__((address_space(3))) void*)l, 16, 0, 0);
}

// ---------------------------------------------------------------------------
// mfma3: OUT[m,n] = bias[n] + sum_k A[m,k]*B[n,k] via 3-term split bf16.
// 256x256 tile, BK=32, 8 waves (2x4), wave tile 128x64, 32x32x16 MFMA.
// Double-buffered LDS (2 x 64 KiB, 1 block/CU), 1 barrier/iter, stage(kt+1)
// issued right after the barrier. Panel-grouped XCD swizzle (round-14).
// Best of 6 tested structures (58-60% MfmaUtil, FETCH 1.23 GB).
// ---------------------------------------------------------------------------
__global__ __launch_bounds__(512, 1) void mfma3(
    const ushort_t* __restrict__ Ah, const ushort_t* __restrict__ Al,
    const ushort_t* __restrict__ Bh, const ushort_t* __restrict__ Bl,
    const float* __restrict__ bias, float* __restrict__ OUT,
    int nkt, int ldout, int nt)
{
    extern __shared__ __align__(16) ushort_t smem[];   // 2 * BUF2SZ ushorts

    const int tid  = threadIdx.x;
    const int wave = tid >> 6;
    const int lane = tid & 63;

    int mtb, ntb;
    {
        const int L = blockIdx.x;
        if ((nt & 7) == 0) {           // bijective panel-grouped XCD swizzle
            const int x = L & 7;       // XCD (hw: id % 8)
            const int s = L >> 3;      // slot within XCD
            mtb = x + 8 * (s / 12);
            ntb = s % 12;
        } else {                       // natural fallback
            mtb = L / 12;
            ntb = L % 12;
        }
    }
    const int wr = wave >> 2;        // 0..1: 128-row slab
    const int wc = wave & 3;         // 0..3: 64-col slab

    f32x16 acc[4][2];
#pragma unroll
    for (int i = 0; i < 4; ++i)
#pragma unroll
        for (int j = 0; j < 2; ++j)
#pragma unroll
            for (int r = 0; r < 16; ++r) acc[i][j][r] = 0.f;

    const size_t a0 = (size_t)(2 * mtb) * nkt * 4096;
    const size_t a1 = a0 + (size_t)nkt * 4096;
    const size_t b0 = (size_t)(2 * ntb) * nkt * 4096;
    const size_t b1 = b0 + (size_t)nkt * 4096;

#define STAGE2(slot, kt_) do {                                      \
        ushort_t* d = smem + (slot) * BUF2SZ;                       \
        const size_t ko = (size_t)(kt_) * 4096 + tid * 8;           \
        gload16(Ah + a0 + ko, d + tid * 8);                         \
        gload16(Ah + a1 + ko, d + 4096 + tid * 8);                  \
        gload16(Al + a0 + ko, d + 8192 + tid * 8);                  \
        gload16(Al + a1 + ko, d + 12288 + tid * 8);                 \
        gload16(Bh + b0 + ko, d + 16384 + tid * 8);                 \
        gload16(Bh + b1 + ko, d + 20480 + tid * 8);                 \
        gload16(Bl + b0 + ko, d + 24576 + tid * 8);                 \
        gload16(Bl + b1 + ko, d + 28672 + tid * 8);                 \
    } while (0)

    const int lrow = lane & 31;          // row/col within 32-subtile
    const int kg   = lane >> 5;          // k-group (8 k values)
    const int aBase = wr * 4096;
    const int bBase = 16384 + (wc >> 1) * 4096;
    const int bCol  = (wc & 1) * 64;

    STAGE2(0, 0);

    for (int kt = 0; kt < nkt; ++kt) {
        asm volatile("s_waitcnt vmcnt(0)" ::: "memory");
        __builtin_amdgcn_sched_barrier(0);
        __builtin_amdgcn_s_barrier();          // stage(kt) visible; prev reads done
        if (kt + 1 < nkt) STAGE2((kt + 1) & 1, kt + 1);

        const ushort_t* p = smem + (kt & 1) * BUF2SZ;
#pragma unroll
        for (int kh = 0; kh < 2; ++kh) {
            const int ko = (kh * 2 + kg) * 1024;
            short8 a_h[4], a_l[4], b_h[2], b_l[2];
#pragma unroll
            for (int ms = 0; ms < 4; ++ms) {
                const int ao = aBase + ko + (ms * 32 + lrow) * 8;
                a_h[ms] = *(const short8*)&p[ao];
                a_l[ms] = *(const short8*)&p[8192 + ao];
            }
#pragma unroll
            for (int ns = 0; ns < 2; ++ns) {
                const int bo = bBase + ko + (bCol + ns * 32 + lrow) * 8;
                b_h[ns] = *(const short8*)&p[bo];
                b_l[ns] = *(const short8*)&p[8192 + bo];
            }
#pragma unroll
            for (int ms = 0; ms < 4; ++ms)
#pragma unroll
                for (int ns = 0; ns < 2; ++ns) {
                    acc[ms][ns] = __builtin_amdgcn_mfma_f32_32x32x16_bf16(a_h[ms], b_h[ns], acc[ms][ns], 0, 0, 0);
                    acc[ms][ns] = __builtin_amdgcn_mfma_f32_32x32x16_bf16(a_h[ms], b_l[ns], acc[ms][ns], 0, 0, 0);
                    acc[ms][ns] = __builtin_amdgcn_mfma_f32_32x32x16_bf16(a_l[ms], b_h[ns], acc[ms][ns], 0, 0, 0);
                }
        }
    }
#undef STAGE2

#pragma unroll
    for (int ms = 0; ms < 4; ++ms)
#pragma unroll
        for (int ns = 0; ns < 2; ++ns) {
            const int col = ntb * 256 + wc * 64 + ns * 32 + (lane & 31);
            const float bv = bias[col];
            const int rowb = mtb * 256 + wr * 128 + ms * 32 + 4 * (lane >> 5);
#pragma unroll
            for (int r = 0; r < 16; ++r) {
                const int row = rowb + (r & 3) + 8 * (r >> 2);
                OUT[(size_t)row * ldout + col] = acc[ms][ns][r] + bv;
            }
        }
}

// ---------------------------------------------------------------------------
// ps_full: psF[m,n] = bias_comb[n] + sum_{k<512} h[m,k]*Wcomb[n,k]
// 64x64 tile, FULL K = 16 kt in 4 rounds, NOW double-buffered (2 x 64 KiB
// dynamic LDS, stage r+1 issued under compute r, mfma3-style) -- hides 3 of
// 4 exposed stage latencies. 176 blocks. Deterministic (fixed kt order).
// ---------------------------------------------------------------------------
__global__ __launch_bounds__(256, 1) void ps_full(
    const ushort_t* __restrict__ hH, const ushort_t* __restrict__ hL,
    const ushort_t* __restrict__ WcH, const ushort_t* __restrict__ WcL,
    const float* __restrict__ bias_comb,
    float* __restrict__ psF)   // [256][2816]
{
    extern __shared__ __align__(16) ushort_t psmem[];   // 2 * PSBUF ushorts

    const int tid  = threadIdx.x;
    const int wave = tid >> 6;
    const int lane = tid & 63;
    const int ntile = blockIdx.x;   // 0..43
    const int mtile = blockIdx.y;   // 0..3
    const int amt = mtile >> 1, arh = mtile & 1;
    const int bmt = ntile >> 1, brh = ntile & 1;
    const int wr = wave >> 1, wc = wave & 1;

    f32x4 acc[2][2];
#pragma unroll
    for (int i = 0; i < 2; ++i)
#pragma unroll
        for (int j = 0; j < 2; ++j) acc[i][j] = (f32x4){0.f, 0.f, 0.f, 0.f};

    const int lw    = wave * 512;
    const int lsrcA = wave * 1024 + arh * 512 + lane * 8;
    const int lsrcB = wave * 1024 + brh * 512 + lane * 8;
    const int kb = lane >> 4;
    const int lr = lane & 15;

    // stage layout (ushort idx in one PSBUF): Ah @0, Al @8192, Bh @16384, Bl @24576
#define STAGE_PS(slot, r_) do {                                           \
        ushort_t* d = psmem + (slot) * PSBUF;                             \
        _Pragma("unroll")                                                 \
        for (int ki_ = 0; ki_ < 4; ++ki_) {                               \
            const int kt_ = (r_) * 4 + ki_;                               \
            const size_t at_ = ((size_t)(amt * NKT_H + kt_)) * 4096;      \
            const size_t bt_ = ((size_t)(bmt * NKT_H + kt_)) * 4096;      \
            gload16(hH  + at_ + lsrcA, d + ki_ * 2048 + lw);              \
            gload16(hL  + at_ + lsrcA, d + 8192 + ki_ * 2048 + lw);       \
            gload16(WcH + bt_ + lsrcB, d + 16384 + ki_ * 2048 + lw);      \
            gload16(WcL + bt_ + lsrcB, d + 24576 + ki_ * 2048 + lw);      \
        }                                                                 \
    } while (0)

    STAGE_PS(0, 0);

    for (int r = 0; r < 4; ++r) {
        asm volatile("s_waitcnt vmcnt(0)" ::: "memory");
        __builtin_amdgcn_sched_barrier(0);
        __builtin_amdgcn_s_barrier();        // stage r visible; prev reads done
        if (r + 1 < 4) STAGE_PS((r + 1) & 1, r + 1);

        const ushort_t* p = psmem + (r & 1) * PSBUF;
#pragma unroll
        for (int ki = 0; ki < 4; ++ki) {
            short8 ah[2], al[2], bh[2], bl[2];
#pragma unroll
            for (int i = 0; i < 2; ++i) {
                const int ao = ki * 2048 + kb * 512 + (wr * 32 + i * 16 + lr) * 8;
                ah[i] = *(const short8*)&p[ao];
                al[i] = *(const short8*)&p[8192 + ao];
            }
#pragma unroll
            for (int j = 0; j < 2; ++j) {
                const int bo = ki * 2048 + kb * 512 + (wc * 32 + j * 16 + lr) * 8;
                bh[j] = *(const short8*)&p[16384 + bo];
                bl[j] = *(const short8*)&p[24576 + bo];
            }
#pragma unroll
            for (int i = 0; i < 2; ++i)
#pragma unroll
                for (int j = 0; j < 2; ++j) {
                    acc[i][j] = __builtin_amdgcn_mfma_f32_16x16x32_bf16(ah[i], bh[j], acc[i][j], 0, 0, 0);
                    acc[i][j] = __builtin_amdgcn_mfma_f32_16x16x32_bf16(ah[i], bl[j], acc[i][j], 0, 0, 0);
                    acc[i][j] = __builtin_amdgcn_mfma_f32_16x16x32_bf16(al[i], bh[j], acc[i][j], 0, 0, 0);
                }
        }
    }
#undef STAGE_PS

    float* out = psF + (size_t)(mtile * 64) * NCOMB + ntile * 64;
#pragma unroll
    for (int i = 0; i < 2; ++i) {
        const int row = wr * 32 + i * 16 + (lane >> 4) * 4;
#pragma unroll
        for (int j = 0; j < 2; ++j) {
            const int col = wc * 32 + j * 16 + (lane & 15);
            const float bv = bias_comb[ntile * 64 + col];
#pragma unroll
            for (int r = 0; r < 4; ++r)
                out[(size_t)(row + r) * NCOMB + col] = acc[i][j][r] + bv;
        }
    }
}

// ---------------------------------------------------------------------------
// ew_gemm: EW[m,n] = sum_k embed[m,k] * Win[n, 4936+k]   (m<152, K=200)
// ---------------------------------------------------------------------------
__global__ __launch_bounds__(256) void ew_gemm(
    const float* __restrict__ embed, const float* __restrict__ Win,
    float* __restrict__ EW)
{
    __shared__ float As[16][68];
    __shared__ float Bs[16][68];
    const int tid = threadIdx.x;
    const int tx  = tid & 15;
    const int ty  = tid >> 4;
    const int n0  = blockIdx.x * 64;
    const int m0  = blockIdx.y * 64;
    const int lrow = tid >> 2;
    const int lk   = (tid & 3) * 4;

    float acc[4][4];
#pragma unroll
    for (int i = 0; i < 4; ++i)
#pragma unroll
        for (int j = 0; j < 4; ++j) acc[i][j] = 0.f;

    for (int k0 = 0; k0 < EMB; k0 += 16) {
        int k = k0 + lk;
        float4 av = {0.f,0.f,0.f,0.f}, bv = {0.f,0.f,0.f,0.f};
        if (k < EMB) {
            int am = m0 + lrow;
            if (am < 152) av = *(const float4*)(embed + (size_t)am * EMB + k);
            bv = *(const float4*)(Win + (size_t)(n0 + lrow) * DE + DIM + k);
        }
        __syncthreads();
        As[lk + 0][lrow] = av.x; As[lk + 1][lrow] = av.y;
        As[lk + 2][lrow] = av.z; As[lk + 3][lrow] = av.w;
        Bs[lk + 0][lrow] = bv.x; Bs[lk + 1][lrow] = bv.y;
        Bs[lk + 2][lrow] = bv.z; Bs[lk + 3][lrow] = bv.w;
        __syncthreads();
#pragma unroll
        for (int kk = 0; kk < 16; ++kk) {
            float4 a4 = *(const float4*)&As[kk][ty * 4];
            float4 b4 = *(const float4*)&Bs[kk][tx * 4];
            float avr[4] = {a4.x, a4.y, a4.z, a4.w};
            float bvr[4] = {b4.x, b4.y, b4.z, b4.w};
#pragma unroll
            for (int i = 0; i < 4; ++i)
#pragma unroll
                for (int j = 0; j < 4; ++j)
                    acc[i][j] = fmaf(avr[i], bvr[j], acc[i][j]);
        }
    }
#pragma unroll
    for (int i = 0; i < 4; ++i) {
        int m = m0 + ty * 4 + i;
        if (m < 152) {
#pragma unroll
            for (int j = 0; j < 4; ++j)
                EW[(size_t)m * SIXH + n0 + tx * 4 + j] = acc[i][j];
        }
    }
}

// ---------------------------------------------------------------------------
// prep_misc: padW[256][512] = Wout rows 0..150 (zero-padded);
//            bias_comb[2816] = b_state (0..2559) | b_out (2560..2710) | 0
// ---------------------------------------------------------------------------
__global__ __launch_bounds__(256) void prep_misc(
    const float* __restrict__ Wout, const float* __restrict__ b_state,
    const float* __restrict__ b_out,
    float* __restrict__ padW, float* __restrict__ bc)
{
    int i = blockIdx.x * 256 + threadIdx.x;
    if (i < 256 * 512) {
        int row = i >> 9;
        padW[i] = (row < NCLS) ? Wout[i] : 0.f;
    }
    if (i < NCOMB) {
        float v;
        if (i < FIVEH)                 v = b_state[i];
        else if (i - FIVEH < NCLS)     v = b_out[i - FIVEH];
        else                           v = 0.f;
        bc[i] = v;
    }
}

// init: c = 0, tiled h hi/lo = 0 (first psF == bias). In-graph -> det.
__global__ __launch_bounds__(256) void init_state(
    float* __restrict__ c, ushort_t* __restrict__ hHt, ushort_t* __restrict__ hLt)
{
    int i = blockIdx.x * 256 + threadIdx.x;
    if (i < BATCH * HID) { c[i] = 0.f; hHt[i] = 0; hLt[i] = 0; }
}

// ---------------------------------------------------------------------------
// step_fused(t): 256 blocks x 1 batch row.
//  0) PREFETCH px/psF/c gate inputs into registers (independent of argmax;
//     their latency hides under the preds read + reduce).
//  1) preds[t-1] = psF[b][2560+cls]; wave-parallel argmax -> commit[t-1].
//  2) gates from prefetched regs + EW[erow]; c,h update; h emits.
// ---------------------------------------------------------------------------
__global__ __launch_bounds__(256) void step_fused(
    const float* __restrict__ px_t,        // [256, 3072]
    const float* __restrict__ EW,          // [152, 3072]
    const float* __restrict__ psF,         // [256, 2816]
    int first,
    ushort_t* __restrict__ hHt, ushort_t* __restrict__ hLt,
    float* __restrict__ c, float* __restrict__ hF,
    float* __restrict__ dists_prev,        // dists[t-1] (unused if first)
    int*   __restrict__ commit_prev)       // commits[t-1] (write; unused if first)
{
    __shared__ float hs[HID];
    __shared__ float preds_s[NCLS + 1];
    __shared__ int   commit_sh;

    const int tid = threadIdx.x;
    const int b   = blockIdx.x;

    const float* px = px_t + (size_t)b * SIXH;
    const float* pp = psF + (size_t)b * NCOMB;

    // ---- prefetch gate inputs (issued before the argmax barriers) ----
    float pxv[2][6], ppv[2][5], cv[2];
#pragma unroll
    for (int it = 0; it < 2; ++it) {
        const int u = it * 256 + tid;
#pragma unroll
        for (int k2 = 0; k2 < 5; ++k2) {
            pxv[it][k2] = px[k2 * HID + u];
            ppv[it][k2] = pp[k2 * HID + u];
        }
        pxv[it][5] = px[5 * HID + u];
        cv[it] = c[(size_t)b * HID + u];
    }

    int erow = 0;
    if (!first) {
        if (tid < NCLS) {
            float pr = pp[2560 + tid];
            preds_s[tid] = pr;
            dists_prev[(size_t)b * NCLS + tid] = pr;
        }
        __syncthreads();
        if (tid < 64) {
            // wave-parallel argmax over classes 1..150, first-max tie rule
            float bv = -__builtin_inff();
            int   bi = NCLS;
            for (int n = 1 + tid; n < NCLS; n += 64) {
                float v = preds_s[n];
                if (v > bv) { bv = v; bi = n; }
            }
#pragma unroll
            for (int off = 32; off; off >>= 1) {
                float ov = __shfl_down(bv, off);
                int   oi = __shfl_down(bi, off);
                if (ov > bv || (ov == bv && oi < bi)) { bv = ov; bi = oi; }
            }
            if (tid == 0) {
                commit_prev[b] = bi;
                commit_sh = bi;
            }
        }
        __syncthreads();
        erow = commit_sh + 1;
    }

    const float* ew = EW + (size_t)erow * SIXH;

#pragma unroll
    for (int it = 0; it < 2; ++it) {
        const int u = it * 256 + tid;
        float p[6];
#pragma unroll
        for (int k2 = 0; k2 < 5; ++k2)
            p[k2] = pxv[it][k2] + ew[k2 * HID + u] + ppv[it][k2];  // pp biased
        p[5] = pxv[it][5] + ew[5 * HID + u];

        float i_g = sigmoidf(p[0]);
        float f_g = sigmoidf(p[1]);
        float m_i = tanhf(p[2]);
        float o_g = sigmoidf(p[3]);
        float c_new = i_g * m_i + f_g * cv[it];
        float outv  = o_g * tanhf(c_new);
        float hw    = sigmoidf(p[4]);
        float h_new = hw * outv + (1.f - hw) * p[5];
        c[(size_t)b * HID + u]  = c_new;
        hF[(size_t)b * HID + u] = h_new;
        hs[u] = h_new;
    }
    __syncthreads();

    // tiled bf16 h emit for next step's ps GEMM
    if (tid < 128) {
        const int half = tid >> 6;
        const int ch   = tid & 63;
        const int mt   = b >> 7;
        const int row  = b & 127;
        const size_t off = ((size_t)(mt * NKT_H + (ch >> 2))) * 4096
                         + (size_t)(ch & 3) * 1024 + (size_t)row * 8;
        alignas(16) ushort_t buf[8];
        if (half == 0) {
#pragma unroll
            for (int e = 0; e < 8; ++e) buf[e] = f2bf_rn(hs[ch * 8 + e]);
            *(uint4*)(hHt + off) = *(const uint4*)buf;
        } else {
#pragma unroll
            for (int e = 0; e < 8; ++e) {
                float x = hs[ch * 8 + e];
                buf[e] = f2bf_rn(x - bf2f(f2bf_rn(x)));
            }
            *(uint4*)(hLt + off) = *(const uint4*)buf;
        }
    }
}

// ---------------------------------------------------------------------------
// finalize_last: preds for t = T-1 from fp32 h, argmax, dists+commits write.
// ---------------------------------------------------------------------------
__global__ __launch_bounds__(192) void finalize_last(
    const float* __restrict__ hF, const float* __restrict__ Wout,
    const float* __restrict__ b_out,
    float* __restrict__ dists_last, int* __restrict__ commits_last)
{
    __shared__ float hsh[HID];
    __shared__ float preds[NCLS + 1];
    const int b = blockIdx.x;
    const int tid = threadIdx.x;

    if (tid < 128) {
        float4 v = *(const float4*)(hF + (size_t)b * HID + tid * 4);
        *(float4*)&hsh[tid * 4] = v;
    }
    __syncthreads();
    if (tid < NCLS) {
        const float* w = Wout + (size_t)tid * HID;
        float s0 = 0.f, s1 = 0.f, s2 = 0.f, s3 = 0.f;
        for (int k = 0; k < HID; k += 4) {
            float4 w4 = *(const float4*)(w + k);
            float4 h4 = *(const float4*)&hsh[k];
            s0 = fmaf(h4.x, w4.x, s0);
            s1 = fmaf(h4.y, w4.y, s1);
            s2 = fmaf(h4.z, w4.z, s2);
            s3 = fmaf(h4.w, w4.w, s3);
        }
        float s = b_out[tid] + ((s0 + s1) + (s2 + s3));
        preds[tid] = s;
        dists_last[(size_t)b * NCLS + tid] = s;
    }
    __syncthreads();
    if (tid == 0) {
        int bi = 1; float bv = preds[1];
        for (int n = 2; n < NCLS; ++n) {
            float v = preds[n];
            if (v > bv) { bv = v; bi = n; }
        }
        commits_last[b] = bi;
    }
}

// ---------------------------------------------------------------------------
__global__ __launch_bounds__(192) void gather_out(
    const float* __restrict__ dists, const int* __restrict__ commits,
    const int* __restrict__ gidx, float* __restrict__ out)
{
    const int i = blockIdx.x;
    const int g = gidx[i];
    if (threadIdx.x < NCLS)
        out[(size_t)i * NCLS + threadIdx.x] = dists[(size_t)g * NCLS + threadIdx.x];
    if (threadIdx.x == NCLS)
        out[(size_t)NPACK * NCLS + i] = (float)commits[g];
}

// ---------------------------------------------------------------------------
extern "C" void kernel_launch(void* const* d_in, const int* in_sizes, int n_in,
                              void* d_out, int out_size, void* d_ws, size_t ws_size,
                              hipStream_t stream)
{
    const float* X      = (const float*)d_in[0];  // [80,256,4936]
    const float* embed  = (const float*)d_in[1];  // [152,200]
    const float* Win    = (const float*)d_in[2];  // [3072,5136]
    const float* b_in   = (const float*)d_in[3];
    const float* Wst    = (const float*)d_in[4];  // [2560,512]
    const float* b_st   = (const float*)d_in[5];
    const float* Wout   = (const float*)d_in[6];  // [151,512]
    const float* b_out  = (const float*)d_in[7];
    const int*   gidx   = (const int*)d_in[8];

    // raise dynamic-LDS caps (idempotent; capture-safe host calls)
    hipFuncSetAttribute((const void*)mfma3,
                        hipFuncAttributeMaxDynamicSharedMemorySize,
                        2 * BUF2SZ * 2);
    hipFuncSetAttribute((const void*)ps_full,
                        hipFuncAttributeMaxDynamicSharedMemorySize,
                        2 * PSBUF * 2);

    const size_t WN  = (size_t)24 * NKT * 4096;     // ushorts per Win-split array
    const size_t WCN = (size_t)22 * NKT_H * 4096;   // ushorts per Wcomb-split array
    const size_t HN  = (size_t)2 * NKT_H * 4096;    // ushorts per h-split array

    ushort_t* Wh  = (ushort_t*)d_ws;
    ushort_t* Wl  = Wh + WN;
    ushort_t* WcH = Wl + WN;
    ushort_t* WcL = WcH + WCN;
    ushort_t* hHt = WcL + WCN;
    ushort_t* hLt = hHt + HN;
    float* EW      = (float*)(hLt + HN);
    float* psF     = EW + (size_t)152 * SIXH;             // 256*2816
    float* bc      = psF + (size_t)BATCH * NCOMB;         // 2816
    float* c       = bc + NCOMB;
    float* hF      = c + (size_t)BATCH * HID;
    float* padW    = hF + (size_t)BATCH * HID;            // 256*512
    float* dists   = padW + (size_t)256 * HID;
    int* commits   = (int*)(dists + (size_t)T_STEPS * BATCH * NCLS);
    char* cbase    = (char*)(commits + T_STEPS * BATCH);

    size_t off = (size_t)(cbase - (char*)d_ws);
    off = (off + 255) & ~(size_t)255;
    const size_t per_t = (size_t)2 * 2 * NKT * 4096 * 2 + (size_t)BATCH * SIXH * 4;
    size_t rem = (ws_size > off) ? (ws_size - off) : 0;
    int CT = (int)(rem / per_t);
    if (CT > T_STEPS) CT = T_STEPS;
    if (CT < 1) CT = 1;

    ushort_t* Xh = (ushort_t*)((char*)d_ws + off);
    ushort_t* Xl = Xh + (size_t)2 * CT * NKT * 4096;
    float* px    = (float*)(Xl + (size_t)2 * CT * NKT * 4096);

    // one-time prep
    convert_split<<<dim3(NKT, 24), 256, 0, stream>>>(Win, DE, DIM, Wh, Wl, NKT);
    convert_split<<<dim3(NKT_H, 20), 256, 0, stream>>>(Wst, HID, HID, WcH, WcL, NKT_H);
    prep_misc<<<512, 256, 0, stream>>>(Wout, b_st, b_out, padW, bc);
    convert_split<<<dim3(NKT_H, 2), 256, 0, stream>>>(
        padW, HID, HID, WcH + (size_t)20 * NKT_H * 4096, WcL + (size_t)20 * NKT_H * 4096, NKT_H);
    ew_gemm<<<dim3(SIXH / 64, 3), 256, 0, stream>>>(embed, Win, EW);
    init_state<<<512, 256, 0, stream>>>(c, hHt, hLt);

    for (int t0 = 0; t0 < T_STEPS; t0 += CT) {
        int nt = T_STEPS - t0;
        if (nt > CT) nt = CT;
        convert_split<<<dim3(NKT, 2 * nt), 256, 0, stream>>>(
            X + (size_t)t0 * BATCH * DIM, DIM, DIM, Xh, Xl, NKT);
        mfma3<<<dim3((SIXH / 256) * nt), 512, 2 * BUF2SZ * 2, stream>>>(
            Xh, Xl, Wh, Wl, b_in, px, NKT, SIXH, nt);
        for (int t = t0; t < t0 + nt; ++t) {
            const int tp = (t > 0) ? t - 1 : 0;
            ps_full<<<dim3(44, 4), 256, 2 * PSBUF * 2, stream>>>(
                hHt, hLt, WcH, WcL, bc, psF);
            step_fused<<<BATCH, 256, 0, stream>>>(
                px + (size_t)(t - t0) * BATCH * SIXH, EW, psF,
                (t == 0) ? 1 : 0, hHt, hLt, c, hF,
                dists + (size_t)tp * BATCH * NCLS, commits + (size_t)tp * BATCH);
        }
    }

    finalize_last<<<BATCH, 192, 0, stream>>>(
        hF, Wout, b_out,
        dists + (size_t)(T_STEPS - 1) * BATCH * NCLS,
        commits + (size_t)(T_STEPS - 1) * BATCH);

    gather_out<<<NPACK, 192, 0, stream>>>(dists, commits, gidx, (float*)d_out);
}